// Round 3
// baseline (241.321 us; speedup 1.0000x reference)
//
#include <hip/hip_runtime.h>

// Problem constants: B=4, C=64, H=256, W=512 (fp32)
constexpr int B = 4;
constexpr int C = 64;
constexpr int H = 256;
constexpr int W = 512;
constexpr int CPB = 16;                     // channels per block
constexpr int CPW = 4;                      // channels per wave
constexpr long long HW = (long long)H * W;  // channel stride in floats

// Deep-prefetch, barrier-free design. Each wave owns 4 channel rows of one
// (b,h). ALL global loads (8 disp dwords + 8 row float4 = 160 B/lane) are
// issued up front and pinned with sched_barrier(0) so the compiler cannot
// sink them (round-2 failure: VGPR=24 proved load sinking). The channel loop
// then runs against in-flight data: each ds_write gets a *counted* vmcnt wait
// for just its channel's two loads; later channels' loads stay outstanding.
// One memory-latency window per wave instead of one per channel.
__global__ __launch_bounds__(256) void spatial_warp_kernel(
    const float* __restrict__ input,   // [B,C,H,W]
    const float* __restrict__ disp,    // [B,1,H,W]
    float* __restrict__ out)           // [B,C,H,W]
{
    __shared__ float s_buf[4][2][W];   // 16 KiB: [wave][double-buf][W]

    const int t    = threadIdx.x;
    const int lane = t & 63;
    const int wid  = t >> 6;

    const int cg   = blockIdx.x & 3;           // C/CPB = 4 channel groups
    const int rest = blockIdx.x >> 2;
    const int h    = rest & (H - 1);
    const int b    = rest >> 8;                // H = 256

    const long long pix    = ((long long)b * H + h) * (long long)W;
    const long long rowoff = (long long)h * W;
    const int c0 = cg * CPB + wid * CPW;

    const float* p0 = input + ((long long)(b * C + c0)) * HW + rowoff;
    float*       q0 = out   + ((long long)(b * C + c0)) * HW + rowoff;

    // ---- issue disp loads first (the param compute depends on them) ----
    const float* drow = disp + pix;
    float dv[8];
#pragma unroll
    for (int j = 0; j < 8; ++j) dv[j] = drow[lane + 64 * j];

    // ---- issue ALL input row loads: 8 x float4 in flight per lane ----
    float4 va[CPW], vb[CPW];
#pragma unroll
    for (int k = 0; k < CPW; ++k) {
        const float4* rp = reinterpret_cast<const float4*>(p0 + (long long)k * HW);
        va[k] = rp[lane];
        vb[k] = rp[64 + lane];
    }
    __builtin_amdgcn_sched_barrier(0);   // pin the load block: nothing crosses

    // ---- per-lane warp params, computed under the input-load latency ----
    // idx_b == idx_a+1 in-bounds; ia==W-1 corner folded into weights
    // (waf=0, wbf=msk, i0=W-2); OOB folded into msk. No selects in data path.
    float waf[8], wbf[8];
    int   addr0[8];
#pragma unroll
    for (int j = 0; j < 8; ++j) {
        const int w     = lane + 64 * j;
        const float ry  = (float)w + dv[j];
        const float ra  = floorf(ry);
        const float wa  = ra + 1.0f - ry;
        const float wb  = ry - ra;
        const float msk = (ry >= 0.0f && ry <= (float)(W - 1)) ? 1.0f : 0.0f;
        const float iaf = fminf(fmaxf(ra, 0.0f), (float)(W - 1));
        const int   ia  = (int)iaf;
        const bool  hi  = (ia >= W - 1);
        const int   i0  = hi ? (W - 2) : ia;
        waf[j]   = hi ? 0.0f : msk * wa;
        wbf[j]   = hi ? msk  : msk * wb;
        addr0[j] = i0 * 4;
    }

    // ---- channel loop: stage ck (counted vmcnt), gather, fma, store ----
#pragma unroll
    for (int k = 0; k < CPW; ++k) {
        float* buf = &s_buf[wid][k & 1][0];
        reinterpret_cast<float4*>(buf)[lane]      = va[k];
        reinterpret_cast<float4*>(buf)[64 + lane] = vb[k];
        // Wave-private LDS, in-order DS pipe: drain lgkm, fence the scheduler
        // (rule: inline-asm lgkmcnt needs a following sched_barrier).
        asm volatile("s_waitcnt lgkmcnt(0)" ::: "memory");
        __builtin_amdgcn_sched_barrier(0);

        float* op = q0 + (long long)k * HW;
        const char* bufc = reinterpret_cast<const char*>(buf);
#pragma unroll
        for (int j = 0; j < 8; ++j) {
            const float fa = *reinterpret_cast<const float*>(bufc + addr0[j]);
            const float fb = *reinterpret_cast<const float*>(bufc + addr0[j] + 4);
            op[lane + 64 * j] = waf[j] * fa + wbf[j] * fb;  // stride-1: coalesced
        }
    }
}

extern "C" void kernel_launch(void* const* d_in, const int* in_sizes, int n_in,
                              void* d_out, int out_size, void* d_ws, size_t ws_size,
                              hipStream_t stream) {
    const float* input = (const float*)d_in[0];   // right_input [B,C,H,W]
    const float* disp  = (const float*)d_in[1];   // disparity_samples [B,1,H,W]
    float* outp = (float*)d_out;

    const int grid = B * H * (C / CPB);           // 4*256*4 = 4096 blocks
    spatial_warp_kernel<<<grid, 256, 0, stream>>>(input, disp, outp);
}

// Round 5
// 235.957 us; speedup vs baseline: 1.0227x; 1.0227x over previous
//
#include <hip/hip_runtime.h>
#include <stdint.h>

// Problem constants: B=4, C=64, H=256, W=512 (fp32)
constexpr int B = 4;
constexpr int C = 64;
constexpr int H = 256;
constexpr int W = 512;
constexpr int RPW = 16;                     // rows per wave-task
constexpr long long HW = (long long)H * W;  // channel stride in floats

// h-sequential streaming design. Each wave owns (b, c, 16 consecutive rows):
// 32 KB contiguous read + 32 KB contiguous write -> long sequential DRAM
// streams instead of 4096 concurrent 2KB bursts strided 512KB (the round-0..3
// structure, which floored at ~81us with every pipe idle -> DRAM-pattern
// bound). Staging via global_load_lds (no VGPR round trip; the compiler
// cannot sink it -- rounds 2/3 failed because reg-prefetches got re-sunk,
// VGPR=24/40 proved it) into wave-private double buffers, hand-counted
// vmcnt waits, zero barriers.
//
// vmcnt FIFO bookkeeping (per wave, in-order retirement):
//   staging of row r = 4 ops (2x input 1KB, 2x disp 1KB); stores = 8
//   un-mergeable global_store_dword per row (64-float-strided per lane).
//   prologue: stage(0) stage(1).  iter r: wait(r) | 8 stores | stage(r+2).
//   outstanding-after-stage(r): r=0 -> stage(1)=4; 1<=r<=14 ->
//   stores(r-1)+stage(r+1) = 8+4 = 12; r=15 -> stores(14) = 8.
template<int K>
__device__ __forceinline__ void vwait() {
    asm volatile("s_waitcnt vmcnt(%0)" :: "i"(K) : "memory");
    __builtin_amdgcn_sched_barrier(0);
}

// Stage one 2KB row (512 floats) into wave-private LDS: 2 x dwordx4 DMA,
// lane l covers bytes [l*16, l*16+16) of each 1KB half. Linear dest (required:
// global_load_lds writes base + lane*size).
__device__ __forceinline__ void stage_row(const float* gsrc, float* ldst, int lane) {
    __builtin_amdgcn_global_load_lds(
        (const __attribute__((address_space(1))) void*)(gsrc + lane * 4),
        (__attribute__((address_space(3))) void*)(ldst),
        16, 0, 0);
    __builtin_amdgcn_global_load_lds(
        (const __attribute__((address_space(1))) void*)(gsrc + 256 + lane * 4),
        (__attribute__((address_space(3))) void*)(ldst + 256),
        16, 0, 0);
}

__global__ __launch_bounds__(256) void spatial_warp_kernel(
    const float* __restrict__ input,   // [B,C,H,W]
    const float* __restrict__ disp,    // [B,1,H,W]
    float* __restrict__ out)           // [B,C,H,W]
{
    __shared__ float s_in[4][2][W];    // 16 KiB: wave-private input double-buf
    __shared__ float s_dp[4][2][W];    // 16 KiB: wave-private disp double-buf

    const int t    = threadIdx.x;
    const int lane = t & 63;
    const int wid  = t >> 6;

    // block -> (b, channel-quad, h-range); wave -> one channel of the quad
    const int hr = blockIdx.x & 15;           // 16 h-ranges of 16 rows
    const int cq = (blockIdx.x >> 4) & 15;    // 16 channel quads
    const int b  = blockIdx.x >> 8;           // 4 batches
    const int c  = cq * 4 + wid;
    const int h0 = hr * RPW;

    const float* gin  = input + ((long long)(b * C + c)) * HW + (long long)h0 * W;
    const float* gdp  = disp  + ((long long)b * H + h0) * (long long)W;
    float*       gout = out   + ((long long)(b * C + c)) * HW + (long long)h0 * W;

    // ---- prologue: stage rows 0 and 1 (FIFO: 8 ops) ----
    stage_row(gin,     &s_in[wid][0][0], lane);
    stage_row(gdp,     &s_dp[wid][0][0], lane);
    stage_row(gin + W, &s_in[wid][1][0], lane);
    stage_row(gdp + W, &s_dp[wid][1][0], lane);

#pragma unroll
    for (int r = 0; r < RPW; ++r) {
        if (r == 0)            vwait<4>();
        else if (r == RPW - 1) vwait<8>();
        else                   vwait<12>();

        const float* si   = &s_in[wid][r & 1][0];
        const float* sd   = &s_dp[wid][r & 1][0];
        float*       orow = gout + (long long)r * W;

#pragma unroll
        for (int j = 0; j < 8; ++j) {
            const int   w   = lane + 64 * j;          // stride-1 lanes everywhere
            const float d   = sd[w];
            const float ry  = (float)w + d;
            const float ra  = floorf(ry);
            const float wa  = ra + 1.0f - ry;
            const float wb  = ry - ra;
            const float msk = (ry >= 0.0f && ry <= (float)(W - 1)) ? 1.0f : 0.0f;
            const float iaf = fminf(fmaxf(ra, 0.0f), (float)(W - 1));
            const int   ia  = (int)iaf;
            const bool  hi  = (ia >= W - 1);
            const int   i0  = hi ? (W - 2) : ia;       // fb carries value at corner
            const float waf = hi ? 0.0f : msk * wa;
            const float wbf = hi ? msk  : msk * wb;
            const float fa  = si[i0];                  // stride-1 LDS gather
            const float fb  = si[i0 + 1];
            __builtin_nontemporal_store(waf * fa + wbf * fb, orow + w);
        }

        if (r + 2 < RPW) {
            // Nothing may cross: the DMA below overwrites slot (r&1), whose
            // ds_reads above have all completed (their consumers, the stores,
            // precede this point and forced the lgkm drain).
            __builtin_amdgcn_sched_barrier(0);
            stage_row(gin + (long long)(r + 2) * W, &s_in[wid][r & 1][0], lane);
            stage_row(gdp + (long long)(r + 2) * W, &s_dp[wid][r & 1][0], lane);
        }
    }
}

extern "C" void kernel_launch(void* const* d_in, const int* in_sizes, int n_in,
                              void* d_out, int out_size, void* d_ws, size_t ws_size,
                              hipStream_t stream) {
    const float* input = (const float*)d_in[0];   // right_input [B,C,H,W]
    const float* disp  = (const float*)d_in[1];   // disparity_samples [B,1,H,W]
    float* outp = (float*)d_out;

    const int grid = B * (C / 4) * (H / RPW);     // 4*16*16 = 1024 blocks, all resident
    spatial_warp_kernel<<<grid, 256, 0, stream>>>(input, disp, outp);
}